// Round 5
// baseline (93.344 us; speedup 1.0000x reference)
//
#include <hip/hip_runtime.h>
#include <hip/hip_bf16.h>
#include <cstdint>

typedef float f32x4 __attribute__((ext_vector_type(4)));
typedef short s16x8 __attribute__((ext_vector_type(8)));
typedef short s16x4 __attribute__((ext_vector_type(4)));

constexpr int B_ = 2, L_ = 2048, D_ = 1024, H_ = 16, DH = 64, HALF = 64;
constexpr int M_ROWS = B_ * L_;   // 4096
constexpr int QKV_N = 3 * D_;     // 3072

__device__ __forceinline__ void gload16(const void* g, void* l) {
    __builtin_amdgcn_global_load_lds(
        (const __attribute__((address_space(1))) unsigned int*)g,
        (__attribute__((address_space(3))) unsigned int*)l, 16, 0, 0);
}

// ---------------- RMSNorm: fp32 [row, 1024] -> bf16 ----------------
__global__ void rmsnorm_kernel(const float* __restrict__ x, const float* __restrict__ wn,
                               __hip_bfloat16* __restrict__ xn) {
    int row = blockIdx.x;
    int t = threadIdx.x;                       // 256 threads, 4 elems each
    const float4* xr = reinterpret_cast<const float4*>(x + (size_t)row * D_);
    float4 v = xr[t];
    float ss = v.x * v.x + v.y * v.y + v.z * v.z + v.w * v.w;
#pragma unroll
    for (int off = 32; off; off >>= 1) ss += __shfl_xor(ss, off);
    __shared__ float red[4];
    if ((t & 63) == 0) red[t >> 6] = ss;
    __syncthreads();
    float tot = red[0] + red[1] + red[2] + red[3];
    float rinv = rsqrtf(tot * (1.0f / D_) + 1e-6f);
    const float4* wr = reinterpret_cast<const float4*>(wn);
    float4 w = wr[t];
    __hip_bfloat16* o = xn + (size_t)row * D_ + t * 4;
    o[0] = __float2bfloat16(v.x * rinv * w.x);
    o[1] = __float2bfloat16(v.y * rinv * w.y);
    o[2] = __float2bfloat16(v.z * rinv * w.z);
    o[3] = __float2bfloat16(v.w * rinv * w.w);
}

// ---------------- fused fp32 -> bf16 convert of both weights ----------------
__global__ void cvt_weights_kernel(const float* __restrict__ wq, const float* __restrict__ wo,
                                   __hip_bfloat16* __restrict__ oq, __hip_bfloat16* __restrict__ oo) {
    constexpr int NQ4 = QKV_N * D_ / 4;        // 786432
    int i = blockIdx.x * blockDim.x + threadIdx.x;
    const float* src; __hip_bfloat16* dst; int j;
    if (i < NQ4) { src = wq; dst = oq; j = i; }
    else         { src = wo; dst = oo; j = i - NQ4; }
    float4 v = reinterpret_cast<const float4*>(src)[j];
    __hip_bfloat16* o = dst + (size_t)j * 4;
    o[0] = __float2bfloat16(v.x);
    o[1] = __float2bfloat16(v.y);
    o[2] = __float2bfloat16(v.z);
    o[3] = __float2bfloat16(v.w);
}

// ---------------- pipelined GEMM: C[M,N] = A[M,K] * Bt[N,K]^T ----------------
// 256 thr = 4 waves (2x2); block tile 128x128, BK=64; counted-vmcnt double buffer.
// EPI 0 (QKV): q,k cols -> Cbf; v cols (>=2048) -> vT[b][h][dh][L] packed 8B stores.
// EPI 1: store f32 + residual to Cf.
template <int EPI>
__global__ __launch_bounds__(256, 2) void gemm_pipe_kernel(const __hip_bfloat16* __restrict__ A,
                                                           const __hip_bfloat16* __restrict__ Bt,
                                                           __hip_bfloat16* __restrict__ Cbf,
                                                           __hip_bfloat16* __restrict__ vT,
                                                           float* __restrict__ Cf,
                                                           const float* __restrict__ resid,
                                                           int M, int N, int K) {
    constexpr int BM = 128, BN = 128;
    constexpr int BUF = (BM + BN) * 128;       // 32 KB per buffer
    __shared__ __align__(16) char smem[2 * BUF];

    const int tid = threadIdx.x;
    const int lane = tid & 63;
    const int wid = tid >> 6;

    // ---- XCD-aware bijective block swizzle (nwg % 8 == 0 for both grids) ----
    int nwg = gridDim.x * gridDim.y;
    int lin = blockIdx.y * gridDim.x + blockIdx.x;
    int cpx = nwg >> 3;
    int swz = (lin & 7) * cpx + (lin >> 3);
    int bx = swz % gridDim.x;
    int by = swz / gridDim.x;

    const int rowBase = by * BM;
    const int colBase = bx * BN;
    const int NTILES = K >> 6;

    // staging: thread t covers (row = t>>3 [+32 per issue], slot q = t&7)
    const int srow = tid >> 3;                  // 0..31
    const int colSw = ((tid & 7) ^ (srow & 7)) << 3;   // inverse-swizzled source col
    const __hip_bfloat16* aG = A + (size_t)(rowBase + srow) * K + colSw;
    const __hip_bfloat16* bG = Bt + (size_t)(colBase + srow) * K + colSw;
    const int dstW = wid << 10;                 // wave-uniform LDS chunk

    const int wm = wid >> 1, wn = wid & 1;
    const int l15 = lane & 15, hi = lane >> 4;
    const int s7 = l15 & 7;
    const int rA = wm * 64 + l15;
    const int rB = wn * 64 + l15;

    f32x4 acc[4][4];
#pragma unroll
    for (int m = 0; m < 4; ++m)
#pragma unroll
        for (int n = 0; n < 4; ++n) acc[m][n] = (f32x4){0.f, 0.f, 0.f, 0.f};

    // prologue: stage tile 0 into buf 0
#pragma unroll
    for (int i = 0; i < 4; ++i) {
        gload16(aG + (size_t)(i * 32) * K, smem + i * 4096 + dstW);
        gload16(bG + (size_t)(i * 32) * K, smem + BM * 128 + i * 4096 + dstW);
    }

    for (int kt = 0; kt < NTILES; ++kt) {
        const int bf = kt & 1;
        __builtin_amdgcn_s_barrier();
        if (kt + 1 < NTILES) {
            char* base = smem + (bf ^ 1) * BUF;
            const __hip_bfloat16* as = aG + (size_t)(kt + 1) * 64;
            const __hip_bfloat16* bs = bG + (size_t)(kt + 1) * 64;
#pragma unroll
            for (int i = 0; i < 4; ++i) {
                gload16(as + (size_t)(i * 32) * K, base + i * 4096 + dstW);
                gload16(bs + (size_t)(i * 32) * K, base + BM * 128 + i * 4096 + dstW);
            }
            asm volatile("s_waitcnt vmcnt(8)" ::: "memory");   // tile kt landed
        } else {
            asm volatile("s_waitcnt vmcnt(0)" ::: "memory");
        }

        const char* ab = smem + bf * BUF;
        const char* bb = ab + BM * 128;
        s16x8 af[4][2], bfr[4][2];
#pragma unroll
        for (int mf = 0; mf < 4; ++mf)
#pragma unroll
            for (int kk = 0; kk < 2; ++kk)
                af[mf][kk] = *(const s16x8*)(ab + (rA + mf * 16) * 128 + (((kk * 4 + hi) ^ s7) << 4));
#pragma unroll
        for (int nf = 0; nf < 4; ++nf)
#pragma unroll
            for (int kk = 0; kk < 2; ++kk)
                bfr[nf][kk] = *(const s16x8*)(bb + (rB + nf * 16) * 128 + (((kk * 4 + hi) ^ s7) << 4));

        __builtin_amdgcn_s_setprio(1);
#pragma unroll
        for (int kk = 0; kk < 2; ++kk)
#pragma unroll
            for (int mf = 0; mf < 4; ++mf)
#pragma unroll
                for (int nf = 0; nf < 4; ++nf)
                    acc[mf][nf] = __builtin_amdgcn_mfma_f32_16x16x32_bf16(af[mf][kk], bfr[nf][kk],
                                                                          acc[mf][nf], 0, 0, 0);
        __builtin_amdgcn_s_setprio(0);
    }

#pragma unroll
    for (int mf = 0; mf < 4; ++mf) {
#pragma unroll
        for (int nf = 0; nf < 4; ++nf) {
            int col = colBase + wn * 64 + nf * 16 + l15;
            int row0 = rowBase + wm * 64 + mf * 16 + 4 * hi;
            if (EPI == 0) {
                if (col < 2 * D_) {              // q,k section (wave-uniform branch)
#pragma unroll
                    for (int r = 0; r < 4; ++r)
                        Cbf[(size_t)(row0 + r) * N + col] = __float2bfloat16(acc[mf][nf][r]);
                } else {                          // v section -> transposed vT
                    int h = (col - 2 * D_) >> 6;
                    int dim = (col - 2 * D_) & 63;
                    int bb2 = row0 >> 11, i0 = row0 & (L_ - 1);
                    s16x4 pk;
#pragma unroll
                    for (int r = 0; r < 4; ++r) {
                        __hip_bfloat16 t = __float2bfloat16(acc[mf][nf][r]);
                        pk[r] = *reinterpret_cast<short*>(&t);
                    }
                    *(s16x4*)(vT + ((size_t)(bb2 * H_ + h) * DH + dim) * L_ + i0) = pk;
                }
            } else {
#pragma unroll
                for (int r = 0; r < 4; ++r)
                    Cf[(size_t)(row0 + r) * N + col] = acc[mf][nf][r] + resid[(size_t)(row0 + r) * N + col];
            }
        }
    }
}

// ---------------- MFMA banded flash attention ----------------
// One block = 128 threads (2 waves) handles (b, h, 64 query rows).
// LDS: K linear-swizzled [192][128B] (24576 B) | V^T [64][512B] swizzled (32768 B).
// Both staged via global_load_lds with inverse-swizzled global source.
// P (bf16, per wave [32][168]) aliases the K region after a barrier.
__global__ __launch_bounds__(128) void attn_mfma_kernel(const __hip_bfloat16* __restrict__ qkv,
                                                        const __hip_bfloat16* __restrict__ vT,
                                                        __hip_bfloat16* __restrict__ attn) {
    __shared__ __align__(16) char smem[57344];
    constexpr int VOFF = 24576;
    int tid = threadIdx.x;
    int lane = tid & 63, w = tid >> 6;
    int tq = blockIdx.x, h = blockIdx.y, b = blockIdx.z;
    int q0 = tq * 64;
    int jg0 = q0 - HALF;
    const __hip_bfloat16* qkvb = qkv + (size_t)(b * L_) * QKV_N;
    const __hip_bfloat16* vTg = vT + (size_t)(b * H_ + h) * DH * L_;   // [64][2048]

    // ---- stage K: rows = keys (192), 8 dim-chunk slots/row, slot s holds chunk s^(row&7)
#pragma unroll
    for (int it = 0; it < 12; ++it) {
        int ob = (it * 2 + w) << 10;
        int o = ob + lane * 16;
        int row = o >> 7;
        int c = ((o >> 4) & 7) ^ (row & 7);
        int jg = jg0 + row;
        int jc = jg < 0 ? 0 : (jg > L_ - 1 ? L_ - 1 : jg);
        gload16(qkvb + (size_t)jc * QKV_N + D_ + h * DH + c * 8, smem + ob);
    }
    // ---- stage V^T: rows = dims (64), 32 key-chunk slots/row (24 used), slot s holds chunk s^(d&7)
#pragma unroll
    for (int it = 0; it < 16; ++it) {
        int ob = (it * 2 + w) << 10;
        int o = ob + lane * 16;
        int d = o >> 9;
        int c = ((o >> 4) & 31) ^ (d & 7);
        int kb = jg0 + c * 8;
        int kc = kb < 0 ? 0 : (kb > L_ - 8 ? L_ - 8 : kb);
        gload16(vTg + (size_t)d * L_ + kc, smem + VOFF + ob);
    }
    __syncthreads();

    int l15 = lane & 15, hi = lane >> 4;

    // ---- Q fragments from global (L2-resident) ----
    s16x8 aq[2][2];
#pragma unroll
    for (int m = 0; m < 2; ++m)
#pragma unroll
        for (int kk = 0; kk < 2; ++kk)
            aq[m][kk] = *(const s16x8*)(qkvb + (size_t)(q0 + 32 * w + 16 * m + l15) * QKV_N
                                        + h * DH + kk * 32 + hi * 8);

    // ---- scores S = Q K^T ----
    f32x4 sc[2][10];
#pragma unroll
    for (int m = 0; m < 2; ++m)
#pragma unroll
        for (int kt = 0; kt < 10; ++kt) sc[m][kt] = (f32x4){0.f, 0.f, 0.f, 0.f};

#pragma unroll
    for (int kt = 0; kt < 10; ++kt) {
        int jl = 32 * w + 16 * kt + l15;
        s16x8 bk0 = *(const s16x8*)(smem + jl * 128 + ((hi ^ (jl & 7)) * 16));
        s16x8 bk1 = *(const s16x8*)(smem + jl * 128 + (((4 + hi) ^ (jl & 7)) * 16));
#pragma unroll
        for (int m = 0; m < 2; ++m) {
            sc[m][kt] = __builtin_amdgcn_mfma_f32_16x16x32_bf16(aq[m][0], bk0, sc[m][kt], 0, 0, 0);
            sc[m][kt] = __builtin_amdgcn_mfma_f32_16x16x32_bf16(aq[m][1], bk1, sc[m][kt], 0, 0, 0);
        }
    }

    // ---- band mask + softmax (rows split across 16-lane groups) ----
#pragma unroll
    for (int m = 0; m < 2; ++m) {
#pragma unroll
        for (int r = 0; r < 4; ++r) {
            int iloc = 32 * w + 16 * m + 4 * hi + r;
            float mx = -1e30f;
#pragma unroll
            for (int kt = 0; kt < 10; ++kt) {
                int jl = 32 * w + 16 * kt + l15;
                int jg = jg0 + jl;
                bool ok = (jl >= iloc) && (jl <= iloc + 2 * HALF) && (jg >= 0) && (jg < L_);
                float s = ok ? sc[m][kt][r] * 0.125f : -1e30f;
                sc[m][kt][r] = s;
                mx = fmaxf(mx, s);
            }
            mx = fmaxf(mx, __shfl_xor(mx, 1));
            mx = fmaxf(mx, __shfl_xor(mx, 2));
            mx = fmaxf(mx, __shfl_xor(mx, 4));
            mx = fmaxf(mx, __shfl_xor(mx, 8));
            float sum = 0.f;
#pragma unroll
            for (int kt = 0; kt < 10; ++kt) {
                float p = __expf(sc[m][kt][r] - mx);
                sc[m][kt][r] = p;
                sum += p;
            }
            sum += __shfl_xor(sum, 1);
            sum += __shfl_xor(sum, 2);
            sum += __shfl_xor(sum, 4);
            sum += __shfl_xor(sum, 8);
            float inv = 1.0f / sum;
#pragma unroll
            for (int kt = 0; kt < 10; ++kt) sc[m][kt][r] *= inv;
        }
    }

    __syncthreads();   // everyone done reading K; P aliases the K region

    // ---- write P (bf16) into per-wave LDS region ----
    {
        __hip_bfloat16* Pw = (__hip_bfloat16*)(smem + w * 10752);
#pragma unroll
        for (int m = 0; m < 2; ++m)
#pragma unroll
            for (int kt = 0; kt < 10; ++kt)
#pragma unroll
                for (int r = 0; r < 4; ++r)
                    Pw[(16 * m + 4 * hi + r) * 168 + 16 * kt + l15] = __float2bfloat16(sc[m][kt][r]);
    }
    __syncthreads();

    // ---- O = P V ----
    f32x4 o[2][4];
#pragma unroll
    for (int m = 0; m < 2; ++m)
#pragma unroll
        for (int nt = 0; nt < 4; ++nt) o[m][nt] = (f32x4){0.f, 0.f, 0.f, 0.f};

#pragma unroll
    for (int kst = 0; kst < 5; ++kst) {
        s16x8 ap[2];
#pragma unroll
        for (int m = 0; m < 2; ++m)
            ap[m] = *(const s16x8*)(smem + w * 10752 + (16 * m + l15) * 336 + (32 * kst + 8 * hi) * 2);
#pragma unroll
        for (int nt = 0; nt < 4; ++nt) {
            int d = 16 * nt + l15;
            int c = 4 * w + 4 * kst + hi;                 // logical key chunk (0..23)
            s16x8 bv = *(const s16x8*)(smem + VOFF + d * 512 + ((c ^ (d & 7)) << 4));
#pragma unroll
            for (int m = 0; m < 2; ++m)
                o[m][nt] = __builtin_amdgcn_mfma_f32_16x16x32_bf16(ap[m], bv, o[m][nt], 0, 0, 0);
        }
    }

    // ---- store ----
#pragma unroll
    for (int m = 0; m < 2; ++m)
#pragma unroll
        for (int nt = 0; nt < 4; ++nt)
#pragma unroll
            for (int r = 0; r < 4; ++r) {
                int rowg = q0 + 32 * w + 16 * m + 4 * hi + r;
                attn[(size_t)(b * L_ + rowg) * D_ + h * DH + 16 * nt + l15] =
                    __float2bfloat16(o[m][nt][r]);
            }
}

extern "C" void kernel_launch(void* const* d_in, const int* in_sizes, int n_in,
                              void* d_out, int out_size, void* d_ws, size_t ws_size,
                              hipStream_t stream) {
    const float* x      = (const float*)d_in[0];
    const float* w_norm = (const float*)d_in[1];
    const float* w_qkv  = (const float*)d_in[2];
    const float* w_out  = (const float*)d_in[3];

    char* ws = (char*)d_ws;
    __hip_bfloat16* xn   = (__hip_bfloat16*)(ws);                        //  8 MiB
    __hip_bfloat16* wq   = (__hip_bfloat16*)(ws + (8u  << 20));          //  6 MiB
    __hip_bfloat16* wo   = (__hip_bfloat16*)(ws + (14u << 20));          //  2 MiB
    __hip_bfloat16* qkv  = (__hip_bfloat16*)(ws + (16u << 20));          // 24 MiB (q,k used)
    __hip_bfloat16* attn = (__hip_bfloat16*)(ws + (40u << 20));          //  8 MiB
    __hip_bfloat16* vT   = (__hip_bfloat16*)(ws + (48u << 20));          //  8 MiB
    float* out = (float*)d_out;

    // fused weight conversion (wq then wo)
    {
        int n4 = (QKV_N * D_ + D_ * D_) / 4;
        cvt_weights_kernel<<<n4 / 256, 256, 0, stream>>>(w_qkv, w_out, wq, wo);
    }

    // RMSNorm
    rmsnorm_kernel<<<M_ROWS, 256, 0, stream>>>(x, w_norm, xn);

    // QKV GEMM: [4096,1024] x [3072,1024]^T -> q,k bf16 + vT transposed
    gemm_pipe_kernel<0><<<dim3(QKV_N / 128, M_ROWS / 128), 256, 0, stream>>>(
        xn, wq, qkv, vT, nullptr, nullptr, M_ROWS, QKV_N, D_);

    // MFMA banded attention -> bf16 [4096,1024]
    attn_mfma_kernel<<<dim3(L_ / 64, H_, B_), 128, 0, stream>>>(qkv, vT, attn);

    // out proj + residual: [4096,1024] x [1024,1024]^T + x -> f32 d_out
    gemm_pipe_kernel<1><<<dim3(D_ / 128, M_ROWS / 128), 256, 0, stream>>>(
        attn, wo, nullptr, nullptr, out, x, M_ROWS, D_, D_);
}

// Round 7
// 92.349 us; speedup vs baseline: 1.0108x; 1.0108x over previous
//
#include <hip/hip_runtime.h>
#include <hip/hip_bf16.h>
#include <cstdint>

typedef float f32x4 __attribute__((ext_vector_type(4)));
typedef short s16x8 __attribute__((ext_vector_type(8)));
typedef short s16x4 __attribute__((ext_vector_type(4)));

constexpr int B_ = 2, L_ = 2048, D_ = 1024, H_ = 16, DH = 64, HALF = 64;
constexpr int M_ROWS = B_ * L_;   // 4096
constexpr int QKV_N = 3 * D_;     // 3072

__device__ __forceinline__ void gload16(const void* g, void* l) {
    __builtin_amdgcn_global_load_lds(
        (const __attribute__((address_space(1))) unsigned int*)g,
        (__attribute__((address_space(3))) unsigned int*)l, 16, 0, 0);
}

// compiler-level fence: block memory-op motion across this point (0 instructions)
__device__ __forceinline__ void cfence() {
    __builtin_amdgcn_sched_barrier(0);
    asm volatile("" ::: "memory");
}

// ---------------- RMSNorm: wave per row, fp32 [row,1024] -> bf16 ----------------
__global__ __launch_bounds__(256) void rmsnorm_kernel(const float* __restrict__ x,
                                                      const float* __restrict__ wn,
                                                      __hip_bfloat16* __restrict__ xn) {
    int w = threadIdx.x >> 6, lane = threadIdx.x & 63;
    int row = blockIdx.x * 4 + w;
    const float4* xr = reinterpret_cast<const float4*>(x + (size_t)row * D_);
    const float4* wr = reinterpret_cast<const float4*>(wn);
    float4 v[4];
    float ss = 0.f;
#pragma unroll
    for (int c = 0; c < 4; ++c) {
        v[c] = xr[c * 64 + lane];
        ss += v[c].x * v[c].x + v[c].y * v[c].y + v[c].z * v[c].z + v[c].w * v[c].w;
    }
#pragma unroll
    for (int off = 32; off; off >>= 1) ss += __shfl_xor(ss, off);
    float rinv = rsqrtf(ss * (1.0f / D_) + 1e-6f);
#pragma unroll
    for (int c = 0; c < 4; ++c) {
        float4 wv = wr[c * 64 + lane];
        s16x4 pk;
        float vals[4] = {v[c].x * rinv * wv.x, v[c].y * rinv * wv.y,
                         v[c].z * rinv * wv.z, v[c].w * rinv * wv.w};
#pragma unroll
        for (int e = 0; e < 4; ++e) {
            __hip_bfloat16 t = __float2bfloat16(vals[e]);
            pk[e] = *reinterpret_cast<short*>(&t);
        }
        *(s16x4*)(xn + (size_t)row * D_ + (c * 64 + lane) * 4) = pk;
    }
}

// ---------------- fused fp32 -> bf16 convert of both weights ----------------
__global__ void cvt_weights_kernel(const float* __restrict__ wq, const float* __restrict__ wo,
                                   __hip_bfloat16* __restrict__ oq, __hip_bfloat16* __restrict__ oo) {
    constexpr int NQ4 = QKV_N * D_ / 4;        // 786432
    int i = blockIdx.x * blockDim.x + threadIdx.x;
    const float* src; __hip_bfloat16* dst; int j;
    if (i < NQ4) { src = wq; dst = oq; j = i; }
    else         { src = wo; dst = oo; j = i - NQ4; }
    float4 v = reinterpret_cast<const float4*>(src)[j];
    s16x4 pk;
    float vals[4] = {v.x, v.y, v.z, v.w};
#pragma unroll
    for (int e = 0; e < 4; ++e) {
        __hip_bfloat16 t = __float2bfloat16(vals[e]);
        pk[e] = *reinterpret_cast<short*>(&t);
    }
    *(s16x4*)(dst + (size_t)j * 4) = pk;
}

// ---------------- pipelined GEMM: C[M,N] = A[M,K] * Bt[N,K]^T ----------------
// 256 thr = 4 waves (2x2); block tile 128 x BN, BK=64; counted-vmcnt double buffer.
// Race-free schedule per K-tile:
//   stage kt+1 -> vmcnt(own kt retired, kt+1 in flight) -> s_barrier (ALL waves'
//   kt loads landed) -> fence -> ds_read+MFMA -> lgkmcnt(0) -> s_barrier (buffer free).
// EPI 0 (QKV, BN=128): q,k cols -> Cbf; v cols (>=2048) -> LDS transpose -> vT 16B stores.
// EPI 1 (BN=64): store f32 + residual to Cf.
template <int EPI, int BN>
__global__ __launch_bounds__(256, 2) void gemm_pipe_kernel(const __hip_bfloat16* __restrict__ A,
                                                           const __hip_bfloat16* __restrict__ Bt,
                                                           __hip_bfloat16* __restrict__ Cbf,
                                                           __hip_bfloat16* __restrict__ vT,
                                                           float* __restrict__ Cf,
                                                           const float* __restrict__ resid,
                                                           int M, int N, int K) {
    constexpr int BM = 128;
    constexpr int NFR = BN / 32;               // B-frags per wave in n-dir
    constexpr int ABYTES = BM * 128;
    constexpr int BBYTES = BN * 128;
    constexpr int BUF = ABYTES + BBYTES;
    constexpr int AISS = BM / 32, BISS = BN / 32, NISS = AISS + BISS;
    __shared__ __align__(16) char smem[2 * BUF];

    const int tid = threadIdx.x;
    const int lane = tid & 63;
    const int wid = tid >> 6;

    // XCD-aware bijective block swizzle (nwg % 8 == 0 for both grids)
    int nwg = gridDim.x * gridDim.y;
    int lin = blockIdx.y * gridDim.x + blockIdx.x;
    int cpx = nwg >> 3;
    int swz = (lin & 7) * cpx + (lin >> 3);
    int bx = swz % gridDim.x;
    int by = swz / gridDim.x;

    const int rowBase = by * BM;
    const int colBase = bx * BN;
    const int NTILES = K >> 6;

    const int srow = tid >> 3;                  // 0..31
    const int colSw = ((tid & 7) ^ (srow & 7)) << 3;   // inverse-swizzled source col
    const __hip_bfloat16* aG = A + (size_t)(rowBase + srow) * K + colSw;
    const __hip_bfloat16* bG = Bt + (size_t)(colBase + srow) * K + colSw;
    const int dstW = wid << 10;

    const int wm = wid >> 1, wn = wid & 1;
    const int l15 = lane & 15, hi = lane >> 4;
    const int s7 = l15 & 7;
    const int rA = wm * 64 + l15;
    const int rB = wn * (BN / 2) + l15;

    f32x4 acc[4][NFR];
#pragma unroll
    for (int m = 0; m < 4; ++m)
#pragma unroll
        for (int n = 0; n < NFR; ++n) acc[m][n] = (f32x4){0.f, 0.f, 0.f, 0.f};

    // prologue: stage tile 0 into buf 0
#pragma unroll
    for (int i = 0; i < AISS; ++i) gload16(aG + (size_t)(i * 32) * K, smem + i * 4096 + dstW);
#pragma unroll
    for (int i = 0; i < BISS; ++i) gload16(bG + (size_t)(i * 32) * K, smem + ABYTES + i * 4096 + dstW);

    for (int kt = 0; kt < NTILES; ++kt) {
        const int bf = kt & 1;
        if (kt + 1 < NTILES) {
            char* base = smem + (bf ^ 1) * BUF;
            const __hip_bfloat16* as = aG + (size_t)(kt + 1) * 64;
            const __hip_bfloat16* bs = bG + (size_t)(kt + 1) * 64;
#pragma unroll
            for (int i = 0; i < AISS; ++i) gload16(as + (size_t)(i * 32) * K, base + i * 4096 + dstW);
#pragma unroll
            for (int i = 0; i < BISS; ++i) gload16(bs + (size_t)(i * 32) * K, base + ABYTES + i * 4096 + dstW);
            if constexpr (NISS == 8)
                asm volatile("s_waitcnt vmcnt(8)" ::: "memory");   // own kt loads retired
            else
                asm volatile("s_waitcnt vmcnt(6)" ::: "memory");
        } else {
            asm volatile("s_waitcnt vmcnt(0)" ::: "memory");
        }
        __builtin_amdgcn_s_barrier();           // ALL waves' kt loads now in LDS
        cfence();                               // no ds_read may hoist above barrier

        const char* ab = smem + bf * BUF;
        const char* bb = ab + ABYTES;
        s16x8 af[4][2], bfr[NFR][2];
#pragma unroll
        for (int mf = 0; mf < 4; ++mf)
#pragma unroll
            for (int kk = 0; kk < 2; ++kk)
                af[mf][kk] = *(const s16x8*)(ab + (rA + mf * 16) * 128 + (((kk * 4 + hi) ^ s7) << 4));
#pragma unroll
        for (int nf = 0; nf < NFR; ++nf)
#pragma unroll
            for (int kk = 0; kk < 2; ++kk)
                bfr[nf][kk] = *(const s16x8*)(bb + (rB + nf * 16) * 128 + (((kk * 4 + hi) ^ s7) << 4));

        __builtin_amdgcn_s_setprio(1);
#pragma unroll
        for (int kk = 0; kk < 2; ++kk)
#pragma unroll
            for (int mf = 0; mf < 4; ++mf)
#pragma unroll
                for (int nf = 0; nf < NFR; ++nf)
                    acc[mf][nf] = __builtin_amdgcn_mfma_f32_16x16x32_bf16(af[mf][kk], bfr[nf][kk],
                                                                          acc[mf][nf], 0, 0, 0);
        __builtin_amdgcn_s_setprio(0);

        asm volatile("s_waitcnt lgkmcnt(0)" ::: "memory");   // all LDS reads sampled
        __builtin_amdgcn_s_barrier();           // buffer bf now safe to overwrite
        cfence();
    }

    if constexpr (EPI == 0) {
        if (colBase < 2 * D_) {                 // q,k section: direct scalar stores
#pragma unroll
            for (int mf = 0; mf < 4; ++mf)
#pragma unroll
                for (int nf = 0; nf < NFR; ++nf) {
                    int col = colBase + wn * (BN / 2) + nf * 16 + l15;
                    int row0 = rowBase + wm * 64 + mf * 16 + 4 * hi;
#pragma unroll
                    for (int r = 0; r < 4; ++r)
                        Cbf[(size_t)(row0 + r) * N + col] = __float2bfloat16(acc[mf][nf][r]);
                }
        } else {                                 // v section: LDS transpose -> vT
            char* Ct = smem;                     // [128 cols][stride 272B]
#pragma unroll
            for (int mf = 0; mf < 4; ++mf)
#pragma unroll
                for (int nf = 0; nf < NFR; ++nf) {
                    int cl = wn * (BN / 2) + nf * 16 + l15;
#pragma unroll
                    for (int r = 0; r < 4; ++r) {
                        int rl = wm * 64 + mf * 16 + 4 * hi + r;
                        __hip_bfloat16 t = __float2bfloat16(acc[mf][nf][r]);
                        *(short*)(Ct + cl * 272 + rl * 2) = *reinterpret_cast<short*>(&t);
                    }
                }
            __syncthreads();
            int cl = tid >> 1, half = tid & 1;
            int gcol = colBase + cl - 2 * D_;
            int hh = gcol >> 6, dd = gcol & 63;
            int bb2 = rowBase >> 11, i0 = rowBase & (L_ - 1);
            __hip_bfloat16* dstp = vT + ((size_t)(bb2 * H_ + hh) * DH + dd) * L_ + i0 + half * 64;
#pragma unroll
            for (int ch = 0; ch < 8; ++ch) {
                s16x8 vv = *(const s16x8*)(Ct + cl * 272 + half * 128 + ch * 16);
                *(s16x8*)(dstp + ch * 8) = vv;
            }
        }
    } else {
#pragma unroll
        for (int mf = 0; mf < 4; ++mf)
#pragma unroll
            for (int nf = 0; nf < NFR; ++nf) {
                int col = colBase + wn * (BN / 2) + nf * 16 + l15;
                int row0 = rowBase + wm * 64 + mf * 16 + 4 * hi;
#pragma unroll
                for (int r = 0; r < 4; ++r)
                    Cf[(size_t)(row0 + r) * N + col] = acc[mf][nf][r] + resid[(size_t)(row0 + r) * N + col];
            }
    }
}

// ---------------- MFMA banded flash attention ----------------
// One block = 128 threads (2 waves) handles (b, h, 64 query rows).
// LDS: K swizzled [192][128B] (24576 B) | V^T [64][384B] swizzled (24576 B) = 48KB.
// Q loads issued first; K staged; V staged; vmcnt(12)+barrier+fence before QK
// (V stays in flight under QK+softmax). P (per wave [32][168] bf16) aliases K.
__global__ __launch_bounds__(128) void attn_mfma_kernel(const __hip_bfloat16* __restrict__ qkv,
                                                        const __hip_bfloat16* __restrict__ vT,
                                                        __hip_bfloat16* __restrict__ attn) {
    __shared__ __align__(16) char smem[49152];
    constexpr int VOFF = 24576;
    int tid = threadIdx.x;
    int lane = tid & 63, w = tid >> 6;
    int tq = blockIdx.x, h = blockIdx.y, b = blockIdx.z;
    int q0 = tq * 64;
    int jg0 = q0 - HALF;
    const __hip_bfloat16* qkvb = qkv + (size_t)(b * L_) * QKV_N;
    const __hip_bfloat16* vTg = vT + (size_t)(b * H_ + h) * DH * L_;   // [64][2048]

    int l15 = lane & 15, hi = lane >> 4;

    // ---- Q fragments first (oldest in vmcnt FIFO) ----
    s16x8 aq[2][2];
#pragma unroll
    for (int m = 0; m < 2; ++m)
#pragma unroll
        for (int kk = 0; kk < 2; ++kk)
            aq[m][kk] = *(const s16x8*)(qkvb + (size_t)(q0 + 32 * w + 16 * m + l15) * QKV_N
                                        + h * DH + kk * 32 + hi * 8);

    // ---- stage K: rows = keys (192), 8 dim-chunk slots/row, slot s = chunk s^(row&7)
#pragma unroll
    for (int it = 0; it < 12; ++it) {
        int ob = (it * 2 + w) << 10;
        int o = ob + lane * 16;
        int row = o >> 7;
        int c = ((o >> 4) & 7) ^ (row & 7);
        int jg = jg0 + row;
        int jc = jg < 0 ? 0 : (jg > L_ - 1 ? L_ - 1 : jg);
        gload16(qkvb + (size_t)jc * QKV_N + D_ + h * DH + c * 8, smem + ob);
    }
    // ---- stage V^T: rows = dims (64), stride 384B, 24 slots; slot s = key-chunk s^(d&7)
#pragma unroll
    for (int it = 0; it < 12; ++it) {
        int ob = (it * 2 + w) << 10;
        int o = ob + lane * 16;
        int d = o / 384;
        int rem = o - d * 384;
        int c = (rem >> 4) ^ (d & 7);
        int kb = jg0 + c * 8;
        int kc = kb < 0 ? 0 : (kb > L_ - 8 ? L_ - 8 : kb);
        gload16(vTg + (size_t)d * L_ + kc, smem + VOFF + ob);
    }
    asm volatile("s_waitcnt vmcnt(12)" ::: "memory");   // own Q + K landed; V in flight
    __builtin_amdgcn_s_barrier();                        // => ALL waves' K landed
    cfence();                                            // no ds_read hoists above

    // ---- scores S = Q K^T ----
    f32x4 sc[2][10];
#pragma unroll
    for (int m = 0; m < 2; ++m)
#pragma unroll
        for (int kt = 0; kt < 10; ++kt) sc[m][kt] = (f32x4){0.f, 0.f, 0.f, 0.f};

#pragma unroll
    for (int kt = 0; kt < 10; ++kt) {
        int jl = 32 * w + 16 * kt + l15;
        s16x8 bk0 = *(const s16x8*)(smem + jl * 128 + ((hi ^ (jl & 7)) * 16));
        s16x8 bk1 = *(const s16x8*)(smem + jl * 128 + (((4 + hi) ^ (jl & 7)) * 16));
#pragma unroll
        for (int m = 0; m < 2; ++m) {
            sc[m][kt] = __builtin_amdgcn_mfma_f32_16x16x32_bf16(aq[m][0], bk0, sc[m][kt], 0, 0, 0);
            sc[m][kt] = __builtin_amdgcn_mfma_f32_16x16x32_bf16(aq[m][1], bk1, sc[m][kt], 0, 0, 0);
        }
    }

    // ---- band mask + softmax (rows split across 16-lane groups) ----
#pragma unroll
    for (int m = 0; m < 2; ++m) {
#pragma unroll
        for (int r = 0; r < 4; ++r) {
            int iloc = 32 * w + 16 * m + 4 * hi + r;
            float mx = -1e30f;
#pragma unroll
            for (int kt = 0; kt < 10; ++kt) {
                int jl = 32 * w + 16 * kt + l15;
                int jg = jg0 + jl;
                bool ok = (jl >= iloc) && (jl <= iloc + 2 * HALF) && (jg >= 0) && (jg < L_);
                float s = ok ? sc[m][kt][r] * 0.125f : -1e30f;
                sc[m][kt][r] = s;
                mx = fmaxf(mx, s);
            }
            mx = fmaxf(mx, __shfl_xor(mx, 1));
            mx = fmaxf(mx, __shfl_xor(mx, 2));
            mx = fmaxf(mx, __shfl_xor(mx, 4));
            mx = fmaxf(mx, __shfl_xor(mx, 8));
            float sum = 0.f;
#pragma unroll
            for (int kt = 0; kt < 10; ++kt) {
                float p = __expf(sc[m][kt][r] - mx);
                sc[m][kt][r] = p;
                sum += p;
            }
            sum += __shfl_xor(sum, 1);
            sum += __shfl_xor(sum, 2);
            sum += __shfl_xor(sum, 4);
            sum += __shfl_xor(sum, 8);
            float inv = 1.0f / sum;
#pragma unroll
            for (int kt = 0; kt < 10; ++kt) sc[m][kt][r] *= inv;
        }
    }

    __syncthreads();   // full drain: V landed (all waves); K reads done (P aliases K)

    // ---- write P (bf16) into per-wave LDS region ----
    {
        __hip_bfloat16* Pw = (__hip_bfloat16*)(smem + w * 10752);
#pragma unroll
        for (int m = 0; m < 2; ++m)
#pragma unroll
            for (int kt = 0; kt < 10; ++kt)
#pragma unroll
                for (int r = 0; r < 4; ++r)
                    Pw[(16 * m + 4 * hi + r) * 168 + 16 * kt + l15] = __float2bfloat16(sc[m][kt][r]);
    }
    __syncthreads();

    // ---- O = P V ----
    f32x4 o[2][4];
#pragma unroll
    for (int m = 0; m < 2; ++m)
#pragma unroll
        for (int nt = 0; nt < 4; ++nt) o[m][nt] = (f32x4){0.f, 0.f, 0.f, 0.f};

#pragma unroll
    for (int kst = 0; kst < 5; ++kst) {
        s16x8 ap[2];
#pragma unroll
        for (int m = 0; m < 2; ++m)
            ap[m] = *(const s16x8*)(smem + w * 10752 + (16 * m + l15) * 336 + (32 * kst + 8 * hi) * 2);
#pragma unroll
        for (int nt = 0; nt < 4; ++nt) {
            int d = 16 * nt + l15;
            int c = 4 * w + 4 * kst + hi;                 // logical key chunk (0..23)
            s16x8 bv = *(const s16x8*)(smem + VOFF + d * 384 + ((c ^ (d & 7)) << 4));
#pragma unroll
            for (int m = 0; m < 2; ++m)
                o[m][nt] = __builtin_amdgcn_mfma_f32_16x16x32_bf16(ap[m], bv, o[m][nt], 0, 0, 0);
        }
    }

    // ---- store ----
#pragma unroll
    for (int m = 0; m < 2; ++m)
#pragma unroll
        for (int nt = 0; nt < 4; ++nt)
#pragma unroll
            for (int r = 0; r < 4; ++r) {
                int rowg = q0 + 32 * w + 16 * m + 4 * hi + r;
                attn[(size_t)(b * L_ + rowg) * D_ + h * DH + 16 * nt + l15] =
                    __float2bfloat16(o[m][nt][r]);
            }
}

extern "C" void kernel_launch(void* const* d_in, const int* in_sizes, int n_in,
                              void* d_out, int out_size, void* d_ws, size_t ws_size,
                              hipStream_t stream) {
    const float* x      = (const float*)d_in[0];
    const float* w_norm = (const float*)d_in[1];
    const float* w_qkv  = (const float*)d_in[2];
    const float* w_out  = (const float*)d_in[3];

    char* ws = (char*)d_ws;
    __hip_bfloat16* xn   = (__hip_bfloat16*)(ws);                        //  8 MiB
    __hip_bfloat16* wq   = (__hip_bfloat16*)(ws + (8u  << 20));          //  6 MiB
    __hip_bfloat16* wo   = (__hip_bfloat16*)(ws + (14u << 20));          //  2 MiB
    __hip_bfloat16* qkv  = (__hip_bfloat16*)(ws + (16u << 20));          // 24 MiB (q,k used)
    __hip_bfloat16* attn = (__hip_bfloat16*)(ws + (40u << 20));          //  8 MiB
    __hip_bfloat16* vT   = (__hip_bfloat16*)(ws + (48u << 20));          //  8 MiB
    float* out = (float*)d_out;

    // fused weight conversion (wq then wo)
    {
        int n4 = (QKV_N * D_ + D_ * D_) / 4;
        cvt_weights_kernel<<<n4 / 256, 256, 0, stream>>>(w_qkv, w_out, wq, wo);
    }

    // RMSNorm (wave per row)
    rmsnorm_kernel<<<M_ROWS / 4, 256, 0, stream>>>(x, w_norm, xn);

    // QKV GEMM: [4096,1024] x [3072,1024]^T -> q,k bf16 + vT transposed
    gemm_pipe_kernel<0, 128><<<dim3(QKV_N / 128, M_ROWS / 128), 256, 0, stream>>>(
        xn, wq, qkv, vT, nullptr, nullptr, M_ROWS, QKV_N, D_);

    // MFMA banded attention -> bf16 [4096,1024]
    attn_mfma_kernel<<<dim3(L_ / 64, H_, B_), 128, 0, stream>>>(qkv, vT, attn);

    // out proj + residual: [4096,1024] x [1024,1024]^T + x -> f32 d_out
    gemm_pipe_kernel<1, 64><<<dim3(D_ / 64, M_ROWS / 128), 256, 0, stream>>>(
        attn, wo, nullptr, nullptr, out, x, M_ROWS, D_, D_);
}

// Round 8
// 86.246 us; speedup vs baseline: 1.0823x; 1.0708x over previous
//
#include <hip/hip_runtime.h>
#include <hip/hip_bf16.h>
#include <cstdint>

typedef float f32x4 __attribute__((ext_vector_type(4)));
typedef float f32x16 __attribute__((ext_vector_type(16)));
typedef short s16x8 __attribute__((ext_vector_type(8)));
typedef short s16x4 __attribute__((ext_vector_type(4)));
typedef unsigned int u32x2 __attribute__((ext_vector_type(2)));
typedef unsigned int u32x4 __attribute__((ext_vector_type(4)));

constexpr int B_ = 2, L_ = 2048, D_ = 1024, H_ = 16, DH = 64, HALF = 64;
constexpr int M_ROWS = B_ * L_;   // 4096
constexpr int QKV_N = 3 * D_;     // 3072

__device__ __forceinline__ void gload16(const void* g, void* l) {
    __builtin_amdgcn_global_load_lds(
        (const __attribute__((address_space(1))) unsigned int*)g,
        (__attribute__((address_space(3))) unsigned int*)l, 16, 0, 0);
}

// compiler-level fence: block memory-op motion across this point (0 instructions)
__device__ __forceinline__ void cfence() {
    __builtin_amdgcn_sched_barrier(0);
    asm volatile("" ::: "memory");
}

// ---------------- fused prep: weight cvt (blocks 0..4095) + RMSNorm (4096..5119) ----------------
__global__ __launch_bounds__(256) void prep_kernel(const float* __restrict__ x,
                                                   const float* __restrict__ wn,
                                                   const float* __restrict__ wq,
                                                   const float* __restrict__ wo,
                                                   __hip_bfloat16* __restrict__ xn,
                                                   __hip_bfloat16* __restrict__ oq,
                                                   __hip_bfloat16* __restrict__ oo) {
    constexpr int NQ4 = QKV_N * D_ / 4;              // 786432
    constexpr int NCVT = NQ4 + D_ * D_ / 4;          // 1048576
    constexpr int CVTBLK = NCVT / 256;               // 4096
    int bid = blockIdx.x;
    if (bid < CVTBLK) {
        int i = bid * 256 + threadIdx.x;
        const float* src; __hip_bfloat16* dst; int j;
        if (i < NQ4) { src = wq; dst = oq; j = i; }
        else         { src = wo; dst = oo; j = i - NQ4; }
        float4 v = reinterpret_cast<const float4*>(src)[j];
        s16x4 pk;
        float vals[4] = {v.x, v.y, v.z, v.w};
#pragma unroll
        for (int e = 0; e < 4; ++e) {
            __hip_bfloat16 t = __float2bfloat16(vals[e]);
            pk[e] = *reinterpret_cast<short*>(&t);
        }
        *(s16x4*)(dst + (size_t)j * 4) = pk;
    } else {
        int w = threadIdx.x >> 6, lane = threadIdx.x & 63;
        int row = (bid - CVTBLK) * 4 + w;
        const float4* xr = reinterpret_cast<const float4*>(x + (size_t)row * D_);
        const float4* wr = reinterpret_cast<const float4*>(wn);
        float4 v[4];
        float ss = 0.f;
#pragma unroll
        for (int c = 0; c < 4; ++c) {
            v[c] = xr[c * 64 + lane];
            ss += v[c].x * v[c].x + v[c].y * v[c].y + v[c].z * v[c].z + v[c].w * v[c].w;
        }
#pragma unroll
        for (int off = 32; off; off >>= 1) ss += __shfl_xor(ss, off);
        float rinv = rsqrtf(ss * (1.0f / D_) + 1e-6f);
#pragma unroll
        for (int c = 0; c < 4; ++c) {
            float4 wv = wr[c * 64 + lane];
            s16x4 pk;
            float vals[4] = {v[c].x * rinv * wv.x, v[c].y * rinv * wv.y,
                             v[c].z * rinv * wv.z, v[c].w * rinv * wv.w};
#pragma unroll
            for (int e = 0; e < 4; ++e) {
                __hip_bfloat16 t = __float2bfloat16(vals[e]);
                pk[e] = *reinterpret_cast<short*>(&t);
            }
            *(s16x4*)(xn + (size_t)row * D_ + (c * 64 + lane) * 4) = pk;
        }
    }
}

// ---------------- pipelined GEMM: C[M,N] = A[M,K] * Bt[N,K]^T ----------------
// (unchanged from round 7 — race-free counted-vmcnt double buffer)
template <int EPI, int BN>
__global__ __launch_bounds__(256, 2) void gemm_pipe_kernel(const __hip_bfloat16* __restrict__ A,
                                                           const __hip_bfloat16* __restrict__ Bt,
                                                           __hip_bfloat16* __restrict__ Cbf,
                                                           __hip_bfloat16* __restrict__ vT,
                                                           float* __restrict__ Cf,
                                                           const float* __restrict__ resid,
                                                           int M, int N, int K) {
    constexpr int BM = 128;
    constexpr int NFR = BN / 32;
    constexpr int ABYTES = BM * 128;
    constexpr int BBYTES = BN * 128;
    constexpr int BUF = ABYTES + BBYTES;
    constexpr int AISS = BM / 32, BISS = BN / 32, NISS = AISS + BISS;
    __shared__ __align__(16) char smem[2 * BUF];

    const int tid = threadIdx.x;
    const int lane = tid & 63;
    const int wid = tid >> 6;

    int nwg = gridDim.x * gridDim.y;
    int lin = blockIdx.y * gridDim.x + blockIdx.x;
    int cpx = nwg >> 3;
    int swz = (lin & 7) * cpx + (lin >> 3);
    int bx = swz % gridDim.x;
    int by = swz / gridDim.x;

    const int rowBase = by * BM;
    const int colBase = bx * BN;
    const int NTILES = K >> 6;

    const int srow = tid >> 3;
    const int colSw = ((tid & 7) ^ (srow & 7)) << 3;
    const __hip_bfloat16* aG = A + (size_t)(rowBase + srow) * K + colSw;
    const __hip_bfloat16* bG = Bt + (size_t)(colBase + srow) * K + colSw;
    const int dstW = wid << 10;

    const int wm = wid >> 1, wn = wid & 1;
    const int l15 = lane & 15, hi = lane >> 4;
    const int s7 = l15 & 7;
    const int rA = wm * 64 + l15;
    const int rB = wn * (BN / 2) + l15;

    f32x4 acc[4][NFR];
#pragma unroll
    for (int m = 0; m < 4; ++m)
#pragma unroll
        for (int n = 0; n < NFR; ++n) acc[m][n] = (f32x4){0.f, 0.f, 0.f, 0.f};

#pragma unroll
    for (int i = 0; i < AISS; ++i) gload16(aG + (size_t)(i * 32) * K, smem + i * 4096 + dstW);
#pragma unroll
    for (int i = 0; i < BISS; ++i) gload16(bG + (size_t)(i * 32) * K, smem + ABYTES + i * 4096 + dstW);

    for (int kt = 0; kt < NTILES; ++kt) {
        const int bf = kt & 1;
        if (kt + 1 < NTILES) {
            char* base = smem + (bf ^ 1) * BUF;
            const __hip_bfloat16* as = aG + (size_t)(kt + 1) * 64;
            const __hip_bfloat16* bs = bG + (size_t)(kt + 1) * 64;
#pragma unroll
            for (int i = 0; i < AISS; ++i) gload16(as + (size_t)(i * 32) * K, base + i * 4096 + dstW);
#pragma unroll
            for (int i = 0; i < BISS; ++i) gload16(bs + (size_t)(i * 32) * K, base + ABYTES + i * 4096 + dstW);
            if constexpr (NISS == 8)
                asm volatile("s_waitcnt vmcnt(8)" ::: "memory");
            else
                asm volatile("s_waitcnt vmcnt(6)" ::: "memory");
        } else {
            asm volatile("s_waitcnt vmcnt(0)" ::: "memory");
        }
        __builtin_amdgcn_s_barrier();
        cfence();

        const char* ab = smem + bf * BUF;
        const char* bb = ab + ABYTES;
        s16x8 af[4][2], bfr[NFR][2];
#pragma unroll
        for (int mf = 0; mf < 4; ++mf)
#pragma unroll
            for (int kk = 0; kk < 2; ++kk)
                af[mf][kk] = *(const s16x8*)(ab + (rA + mf * 16) * 128 + (((kk * 4 + hi) ^ s7) << 4));
#pragma unroll
        for (int nf = 0; nf < NFR; ++nf)
#pragma unroll
            for (int kk = 0; kk < 2; ++kk)
                bfr[nf][kk] = *(const s16x8*)(bb + (rB + nf * 16) * 128 + (((kk * 4 + hi) ^ s7) << 4));

        __builtin_amdgcn_s_setprio(1);
#pragma unroll
        for (int kk = 0; kk < 2; ++kk)
#pragma unroll
            for (int mf = 0; mf < 4; ++mf)
#pragma unroll
                for (int nf = 0; nf < NFR; ++nf)
                    acc[mf][nf] = __builtin_amdgcn_mfma_f32_16x16x32_bf16(af[mf][kk], bfr[nf][kk],
                                                                          acc[mf][nf], 0, 0, 0);
        __builtin_amdgcn_s_setprio(0);

        asm volatile("s_waitcnt lgkmcnt(0)" ::: "memory");
        __builtin_amdgcn_s_barrier();
        cfence();
    }

    if constexpr (EPI == 0) {
        if (colBase < 2 * D_) {
#pragma unroll
            for (int mf = 0; mf < 4; ++mf)
#pragma unroll
                for (int nf = 0; nf < NFR; ++nf) {
                    int col = colBase + wn * (BN / 2) + nf * 16 + l15;
                    int row0 = rowBase + wm * 64 + mf * 16 + 4 * hi;
#pragma unroll
                    for (int r = 0; r < 4; ++r)
                        Cbf[(size_t)(row0 + r) * N + col] = __float2bfloat16(acc[mf][nf][r]);
                }
        } else {
            char* Ct = smem;
#pragma unroll
            for (int mf = 0; mf < 4; ++mf)
#pragma unroll
                for (int nf = 0; nf < NFR; ++nf) {
                    int cl = wn * (BN / 2) + nf * 16 + l15;
#pragma unroll
                    for (int r = 0; r < 4; ++r) {
                        int rl = wm * 64 + mf * 16 + 4 * hi + r;
                        __hip_bfloat16 t = __float2bfloat16(acc[mf][nf][r]);
                        *(short*)(Ct + cl * 272 + rl * 2) = *reinterpret_cast<short*>(&t);
                    }
                }
            __syncthreads();
            int cl = tid >> 1, half = tid & 1;
            int gcol = colBase + cl - 2 * D_;
            int hh = gcol >> 6, dd = gcol & 63;
            int bb2 = rowBase >> 11, i0 = rowBase & (L_ - 1);
            __hip_bfloat16* dstp = vT + ((size_t)(bb2 * H_ + hh) * DH + dd) * L_ + i0 + half * 64;
#pragma unroll
            for (int ch = 0; ch < 8; ++ch) {
                s16x8 vv = *(const s16x8*)(Ct + cl * 272 + half * 128 + ch * 16);
                *(s16x8*)(dstp + ch * 8) = vv;
            }
        }
    } else {
#pragma unroll
        for (int mf = 0; mf < 4; ++mf)
#pragma unroll
            for (int nf = 0; nf < NFR; ++nf) {
                int col = colBase + wn * (BN / 2) + nf * 16 + l15;
                int row0 = rowBase + wm * 64 + mf * 16 + 4 * hi;
#pragma unroll
                for (int r = 0; r < 4; ++r)
                    Cf[(size_t)(row0 + r) * N + col] = acc[mf][nf][r] + resid[(size_t)(row0 + r) * N + col];
            }
    }
}

// ---------------- barrier-free LDS-free MFMA banded attention ----------------
// 128 thr = 2 waves; wave w owns 32 q rows (qbase = 64*blockIdx.x + 32w).
// Swapped QK^T via 32x32x16: T[key][q], C-layout col=lane&31=q (one q per lane),
// row = (r&3)+8*(r>>2)+4*(lane>>5). Softmax fully in-register + 1 shfl_xor(32).
// P repack to PV B-frag via cvt_pk_bf16_f32 pairs (r,r+1)+(r+4,r+5) and
// permlane32_swap (m214v22 recipe). K,Q direct from qkv (L2), V direct from vT.
__global__ __launch_bounds__(128, 2) void attn_mfma_kernel(const __hip_bfloat16* __restrict__ qkv,
                                                           const __hip_bfloat16* __restrict__ vT,
                                                           __hip_bfloat16* __restrict__ attn) {
    int tid = threadIdx.x;
    int w = tid >> 6;
    int lane = tid & 63;
    int l31 = lane & 31, hi1 = lane >> 5;
    int tq = blockIdx.x, h = blockIdx.y, b = blockIdx.z;
    int qbase = tq * 64 + 32 * w;
    int kb = qbase - HALF;                 // key window start (160 keys)
    int qg = qbase + l31;                  // this lane's q row
    const __hip_bfloat16* qkvb = qkv + (size_t)(b * L_) * QKV_N;
    const __hip_bfloat16* vTg = vT + (size_t)(b * H_ + h) * DH * L_;   // [64][L]

    // ---- Q fragments: B-operand, lane(l31,hi1) = Q[qg][16kk + 8hi1 + e] ----
    s16x8 qf[4];
#pragma unroll
    for (int kk = 0; kk < 4; ++kk)
        qf[kk] = *(const s16x8*)(qkvb + (size_t)qg * QKV_N + h * DH + kk * 16 + hi1 * 8);

    // ---- T = K Q^T (swapped): 5 key-tiles of 32 ----
    f32x16 T[5];
#pragma unroll
    for (int kt = 0; kt < 5; ++kt) T[kt] = (f32x16)(0.f);
#pragma unroll
    for (int kt = 0; kt < 5; ++kt) {
        int keyg = kb + 32 * kt + l31;
        int kc = keyg < 0 ? 0 : (keyg > L_ - 1 ? L_ - 1 : keyg);
        const __hip_bfloat16* kp = qkvb + (size_t)kc * QKV_N + D_ + h * DH + hi1 * 8;
#pragma unroll
        for (int kk = 0; kk < 4; ++kk) {
            s16x8 kf = *(const s16x8*)(kp + kk * 16);
            T[kt] = __builtin_amdgcn_mfma_f32_32x32x16_bf16(kf, qf[kk], T[kt], 0, 0, 0);
        }
    }

    // ---- band mask + in-register softmax (lane owns q=qg; keys (r&3)+8(r>>2)+4hi1) ----
    float mx = -1e30f;
#pragma unroll
    for (int kt = 0; kt < 5; ++kt) {
#pragma unroll
        for (int r = 0; r < 16; ++r) {
            int koff = (r & 3) + 8 * (r >> 2) + 4 * hi1;
            int keyg = kb + 32 * kt + koff;
            int del = keyg - qg;
            bool ok = (del >= -HALF) && (del <= HALF) && (keyg >= 0) && (keyg < L_);
            float t = ok ? T[kt][r] * 0.125f : -1e30f;
            T[kt][r] = t;
            mx = fmaxf(mx, t);
        }
    }
    mx = fmaxf(mx, __shfl_xor(mx, 32));
    float sum = 0.f;
#pragma unroll
    for (int kt = 0; kt < 5; ++kt) {
#pragma unroll
        for (int r = 0; r < 16; ++r) {
            float p = __expf(T[kt][r] - mx);
            T[kt][r] = p;
            sum += p;
        }
    }
    sum += __shfl_xor(sum, 32);
    float inv = 1.0f / sum;

    // ---- pack P into PV B-frags: pairs (8s+i,8s+i+1) ; swap (P0,P2),(P1,P3) ----
    u32x4 pu[10];
#pragma unroll
    for (int kt = 0; kt < 5; ++kt) {
#pragma unroll
        for (int s = 0; s < 2; ++s) {
            unsigned P0, P1, P2, P3;
            asm("v_cvt_pk_bf16_f32 %0, %1, %2" : "=v"(P0) : "v"(T[kt][8 * s + 0]), "v"(T[kt][8 * s + 1]));
            asm("v_cvt_pk_bf16_f32 %0, %1, %2" : "=v"(P1) : "v"(T[kt][8 * s + 2]), "v"(T[kt][8 * s + 3]));
            asm("v_cvt_pk_bf16_f32 %0, %1, %2" : "=v"(P2) : "v"(T[kt][8 * s + 4]), "v"(T[kt][8 * s + 5]));
            asm("v_cvt_pk_bf16_f32 %0, %1, %2" : "=v"(P3) : "v"(T[kt][8 * s + 6]), "v"(T[kt][8 * s + 7]));
            u32x2 sA = __builtin_amdgcn_permlane32_swap(P0, P2, false, false);
            u32x2 sB = __builtin_amdgcn_permlane32_swap(P1, P3, false, false);
            pu[2 * kt + s] = (u32x4){sA[0], sB[0], sA[1], sB[1]};
        }
    }

    // ---- O^T = V^T P^T : A = V^T[d][key] direct from vT, B = packed P ----
    f32x16 O[2];
#pragma unroll
    for (int dt = 0; dt < 2; ++dt) O[dt] = (f32x16)(0.f);
#pragma unroll
    for (int t = 0; t < 10; ++t) {
        int kv = kb + 16 * t + 8 * hi1;
        kv = kv < 0 ? 0 : (kv > L_ - 8 ? L_ - 8 : kv);
        s16x8 pf = __builtin_bit_cast(s16x8, pu[t]);
#pragma unroll
        for (int dt = 0; dt < 2; ++dt) {
            s16x8 vf = *(const s16x8*)(vTg + (size_t)(32 * dt + l31) * L_ + kv);
            O[dt] = __builtin_amdgcn_mfma_f32_32x32x16_bf16(vf, pf, O[dt], 0, 0, 0);
        }
    }

    // ---- store: O^T rows = d (runs of 4), col = q = l31; scale by inv ----
    __hip_bfloat16* ob = attn + (size_t)(b * L_ + qg) * D_ + h * DH;
#pragma unroll
    for (int dt = 0; dt < 2; ++dt) {
#pragma unroll
        for (int rr = 0; rr < 4; ++rr) {
            s16x4 pk4;
#pragma unroll
            for (int j = 0; j < 4; ++j) {
                __hip_bfloat16 tb = __float2bfloat16(O[dt][4 * rr + j] * inv);
                pk4[j] = *reinterpret_cast<short*>(&tb);
            }
            *(s16x4*)(ob + 32 * dt + 8 * rr + 4 * hi1) = pk4;
        }
    }
}

extern "C" void kernel_launch(void* const* d_in, const int* in_sizes, int n_in,
                              void* d_out, int out_size, void* d_ws, size_t ws_size,
                              hipStream_t stream) {
    const float* x      = (const float*)d_in[0];
    const float* w_norm = (const float*)d_in[1];
    const float* w_qkv  = (const float*)d_in[2];
    const float* w_out  = (const float*)d_in[3];

    char* ws = (char*)d_ws;
    __hip_bfloat16* xn   = (__hip_bfloat16*)(ws);                        //  8 MiB
    __hip_bfloat16* wq   = (__hip_bfloat16*)(ws + (8u  << 20));          //  6 MiB
    __hip_bfloat16* wo   = (__hip_bfloat16*)(ws + (14u << 20));          //  2 MiB
    __hip_bfloat16* qkv  = (__hip_bfloat16*)(ws + (16u << 20));          // 24 MiB (q,k used)
    __hip_bfloat16* attn = (__hip_bfloat16*)(ws + (40u << 20));          //  8 MiB
    __hip_bfloat16* vT   = (__hip_bfloat16*)(ws + (48u << 20));          //  8 MiB
    float* out = (float*)d_out;

    // fused weight conversion + RMSNorm
    prep_kernel<<<4096 + M_ROWS / 4, 256, 0, stream>>>(x, w_norm, w_qkv, w_out, xn, wq, wo);

    // QKV GEMM: [4096,1024] x [3072,1024]^T -> q,k bf16 + vT transposed
    gemm_pipe_kernel<0, 128><<<dim3(QKV_N / 128, M_ROWS / 128), 256, 0, stream>>>(
        xn, wq, qkv, vT, nullptr, nullptr, M_ROWS, QKV_N, D_);

    // MFMA banded attention -> bf16 [4096,1024]
    attn_mfma_kernel<<<dim3(L_ / 64, H_, B_), 128, 0, stream>>>(qkv, vT, attn);

    // out proj + residual: [4096,1024] x [1024,1024]^T + x -> f32 d_out
    gemm_pipe_kernel<1, 64><<<dim3(D_ / 64, M_ROWS / 128), 256, 0, stream>>>(
        attn, wo, nullptr, nullptr, out, x, M_ROWS, D_, D_);
}